// Round 1
// baseline (4033.557 us; speedup 1.0000x reference)
//
#include <hip/hip_runtime.h>
#include <hip/hip_bf16.h>
#include <math.h>

#define HW   16384
#define WD   128
#define DIM  384
#define NB   8
#define NH   8
#define NC   48
#define NPIX (NB*HW)        // 131072
#define MAT  (DIM*DIM)      // 147456

typedef __hip_bfloat16 bf16;

__device__ __forceinline__ float b2f(bf16 x){ return __bfloat162float(x); }
__device__ __forceinline__ bf16  f2b(float x){ return __float2bfloat16(x); }

// ---------------- zero small atomic targets ----------------
__global__ void k_zero(float* p, int n){
  int i = blockIdx.x*256 + threadIdx.x;
  if(i < n) p[i] = 0.f;
}

// ---------------- LayerNorm stats (per pixel over 384 channels) ----------------
__global__ __launch_bounds__(256) void k_stats(const float* __restrict__ T,
                                               const float* __restrict__ C,
                                               float* __restrict__ mu,
                                               float* __restrict__ rstd){
  int t = threadIdx.x;
  int P = blockIdx.x*256 + t;                 // global pixel 0..131071
  const float* src = (blockIdx.y == 0) ? T : C;
  int b = P >> 14, p = P & (HW-1);
  const float* base = src + (size_t)b*DIM*HW + p;
  float s = 0.f, ss = 0.f;
  for(int c = 0; c < DIM; c++){
    float v = base[(size_t)c*HW];
    s += v; ss += v*v;
  }
  float m   = s * (1.f/DIM);
  float var = ss * (1.f/DIM) - m*m;
  float rs  = rsqrtf(var + 1e-5f);
  int o = blockIdx.y*NPIX + P;
  mu[o] = m; rstd[o] = rs;
}

// ---------------- fold LN affine into conv weights ----------------
// W'[o,c] = W[o,c]*lnw[c];  c1[o] = sum_c W[o,c]*lnb[c] + convb[o];  c2[o] = sum_c W'[o,c]
__global__ void k_prep(const float* tq_w, const float* ck_w, const float* cv_w,
                       const float* tq_b, const float* ck_b, const float* cv_b,
                       const float* tn_w, const float* tn_b,
                       const float* cn_w, const float* cn_b,
                       float* Wp, float* c1, float* c2){
  int o = blockIdx.x, conv = blockIdx.y, t = threadIdx.x;
  const float* W  = conv==0 ? tq_w : (conv==1 ? ck_w : cv_w);
  const float* cb = conv==0 ? tq_b : (conv==1 ? ck_b : cv_b);
  const float* lw = conv==0 ? tn_w : cn_w;
  const float* lb = conv==0 ? tn_b : cn_b;
  float s1 = 0.f, s2 = 0.f;
  for(int c = t; c < DIM; c += 64){
    float w  = W[o*DIM + c];
    float wp = w * lw[c];
    Wp[conv*MAT + o*DIM + c] = wp;
    s1 += w * lb[c];
    s2 += wp;
  }
  for(int off = 32; off; off >>= 1){ s1 += __shfl_down(s1, off); s2 += __shfl_down(s2, off); }
  if(t == 0){ c1[conv*DIM + o] = s1 + cb[o]; c2[conv*DIM + o] = s2; }
}

// ---------------- tiled GEMM, 64x64 tile, 4x4 micro ----------------
// MODE 0: conv1x1 with LN fold; B = raw fp32 input; out bf16
// MODE 1: final fused (W2 @ v1) + proj_b + residual; B = bf16 v1; out fp32
template<int MODE>
__global__ __launch_bounds__(256) void k_gemm(
    const float* __restrict__ Bf, const bf16* __restrict__ Bh,
    const float* __restrict__ A,  const float* __restrict__ bias,
    const float* __restrict__ c2, const float* __restrict__ mu,
    const float* __restrict__ rstd, const float* __restrict__ resid,
    bf16* __restrict__ dsth, float* __restrict__ dstf){
  __shared__ float As[16][68];   // [kc][m], +4 pad keeps float4 alignment, no 4-way conflicts
  __shared__ float Bs[16][68];   // [kc][n]
  int t  = threadIdx.x;
  int tx = t & 15, ty = t >> 4;
  int b  = blockIdx.z;
  int o0 = blockIdx.y*64, p0 = blockIdx.x*64;
  const float* Aw = A + (MODE==1 ? (size_t)b*MAT : (size_t)0);
  float acc[4][4] = {};
  for(int k0 = 0; k0 < DIM; k0 += 16){
    #pragma unroll
    for(int i = 0; i < 4; i++){
      int idx = t + i*256;
      int kc = idx & 15, m = idx >> 4;
      As[kc][m] = Aw[(o0+m)*DIM + k0+kc];
    }
    #pragma unroll
    for(int i = 0; i < 4; i++){
      int idx = t + i*256;
      int n = idx & 63, kc = idx >> 6;
      size_t off = (size_t)(b*DIM + k0+kc)*HW + p0 + n;
      Bs[kc][n] = (MODE==0) ? Bf[off] : b2f(Bh[off]);
    }
    __syncthreads();
    #pragma unroll
    for(int kc = 0; kc < 16; kc++){
      float4 a4 = *(const float4*)&As[kc][ty*4];
      float4 b4 = *(const float4*)&Bs[kc][tx*4];
      float av[4] = {a4.x, a4.y, a4.z, a4.w};
      float bv[4] = {b4.x, b4.y, b4.z, b4.w};
      #pragma unroll
      for(int i = 0; i < 4; i++)
        #pragma unroll
        for(int j = 0; j < 4; j++)
          acc[i][j] = fmaf(av[i], bv[j], acc[i][j]);
    }
    __syncthreads();
  }
  #pragma unroll
  for(int i = 0; i < 4; i++){
    int o = o0 + ty*4 + i;
    #pragma unroll
    for(int j = 0; j < 4; j++){
      int p = p0 + tx*4 + j;
      size_t oidx = (size_t)(b*DIM + o)*HW + p;
      if(MODE == 0){
        int P = b*HW + p;
        float rs = rstd[P], mm = mu[P];
        float v = rs*acc[i][j] + bias[o] - mm*rs*c2[o];
        dsth[oidx] = f2b(v);
      } else {
        dstf[oidx] = acc[i][j] + bias[o] + resid[oidx];
      }
    }
  }
}

// ---------------- depthwise 3x3, SAME, NCHW; optional sumsq for l2norm fold ----------------
__global__ __launch_bounds__(256) void k_dw(const bf16* __restrict__ src, bf16* __restrict__ dst,
                                            const float* __restrict__ dw, const float* __restrict__ db,
                                            float* __restrict__ nrm){
  __shared__ float red[4];
  int t = threadIdx.x;
  int c = blockIdx.y, b = blockIdx.z;
  int p = blockIdx.x*256 + t;
  int y = p >> 7, x = p & 127;
  size_t base = (size_t)(b*DIM + c)*HW;
  float w[9];
  #pragma unroll
  for(int i = 0; i < 9; i++) w[i] = dw[c*9 + i];
  float s = db[c];
  #pragma unroll
  for(int dy = 0; dy < 3; dy++){
    int yy = y + dy - 1;
    if(yy < 0 || yy > 127) continue;
    #pragma unroll
    for(int dx = 0; dx < 3; dx++){
      int xx = x + dx - 1;
      if(xx < 0 || xx > 127) continue;
      s = fmaf(w[dy*3+dx], b2f(src[base + yy*WD + xx]), s);
    }
  }
  dst[base + p] = f2b(s);
  if(nrm){
    float v = s*s;
    for(int off = 32; off; off >>= 1) v += __shfl_down(v, off);
    if((t & 63) == 0) red[t >> 6] = v;
    __syncthreads();
    if(t == 0) atomicAdd(&nrm[b*DIM + c], red[0]+red[1]+red[2]+red[3]);
  }
}

// ---------------- attn = q @ k^T over n (unnormalized; norms folded later) ----------------
__global__ __launch_bounds__(64) void k_attn(const bf16* __restrict__ q, const bf16* __restrict__ k,
                                             float* __restrict__ attn){
  __shared__ float qs[48][68];
  __shared__ float kss[48][68];
  int t = threadIdx.x;
  int split = blockIdx.x;                 // 16-way K split
  int h = blockIdx.y, b = blockIdx.z;
  int tx = t & 7, ty = t >> 3;
  int c0 = ty*6, d0 = tx*6;               // 6x6 outputs per thread
  float acc[6][6] = {};
  size_t rb = (size_t)(b*DIM + h*NC)*HW;
  int n0beg = split*1024;
  for(int n0 = n0beg; n0 < n0beg + 1024; n0 += 64){
    for(int i = 0; i < 48; i++){
      qs [i][t] = b2f(q[rb + (size_t)i*HW + n0 + t]);
      kss[i][t] = b2f(k[rb + (size_t)i*HW + n0 + t]);
    }
    __syncthreads();
    for(int nn = 0; nn < 64; nn += 4){
      float4 qa[6], kb[6];
      #pragma unroll
      for(int i = 0; i < 6; i++){
        qa[i] = *(const float4*)&qs [c0+i][nn];
        kb[i] = *(const float4*)&kss[d0+i][nn];
      }
      #pragma unroll
      for(int i = 0; i < 6; i++)
        #pragma unroll
        for(int j = 0; j < 6; j++){
          acc[i][j] = fmaf(qa[i].x, kb[j].x, acc[i][j]);
          acc[i][j] = fmaf(qa[i].y, kb[j].y, acc[i][j]);
          acc[i][j] = fmaf(qa[i].z, kb[j].z, acc[i][j]);
          acc[i][j] = fmaf(qa[i].w, kb[j].w, acc[i][j]);
        }
    }
    __syncthreads();
  }
  float* ab = attn + (size_t)(b*NH + h)*NC*NC;
  #pragma unroll
  for(int i = 0; i < 6; i++)
    #pragma unroll
    for(int j = 0; j < 6; j++)
      atomicAdd(&ab[(c0+i)*NC + d0+j], acc[i][j]);
}

// ---------------- P = sum_i a_i * softmax(mask_i(attn_scaled)) ----------------
__global__ void k_pmat(const float* __restrict__ attn, const float* __restrict__ nq,
                       const float* __restrict__ nk, const float* __restrict__ tptr,
                       const float* __restrict__ a1p, const float* __restrict__ a2p,
                       const float* __restrict__ a3p, const float* __restrict__ a4p,
                       float* __restrict__ P){
  int t = threadIdx.x;
  int h = blockIdx.x, b = blockIdx.y;
  __shared__ float nkv[48];
  if(t < 48) nkv[t] = fmaxf(sqrtf(nk[b*DIM + h*NC + t]), 1e-12f);
  __syncthreads();
  if(t >= 48) return;
  int c = t;
  float temp = tptr[0];
  float nqc = fmaxf(sqrtf(nq[b*DIM + h*NC + c]), 1e-12f);
  const float* row = attn + ((size_t)(b*NH + h)*NC + c)*NC;
  float r[48], s[48];
  for(int d = 0; d < 48; d++){
    float v = row[d] * temp / (nqc * nkv[d]);
    r[d] = v; s[d] = v;
  }
  // insertion sort descending (48 elems, tiny kernel)
  for(int i = 1; i < 48; i++){
    float key = s[i]; int j = i-1;
    while(j >= 0 && s[j] < key){ s[j+1] = s[j]; j--; }
    s[j+1] = key;
  }
  float m  = s[0];
  float t1 = s[23], t2 = s[31], t3 = s[35], t4 = s[37];   // k-th largest, k=24/32/36/38
  float d1 = 0.f, d2 = 0.f, d3 = 0.f, d4 = 0.f;
  for(int d = 0; d < 48; d++){
    float e = expf(r[d] - m);
    s[d] = e;                     // reuse as exp cache
    if(r[d] >= t1) d1 += e;
    if(r[d] >= t2) d2 += e;
    if(r[d] >= t3) d3 += e;
    if(r[d] >= t4) d4 += e;
  }
  float w1 = a1p[0]/d1, w2 = a2p[0]/d2, w3 = a3p[0]/d3, w4 = a4p[0]/d4;
  float* Pr = P + ((size_t)(b*NH + h)*NC + c)*NC;
  for(int d = 0; d < 48; d++){
    float wsum = 0.f;
    if(r[d] >= t1) wsum += w1;
    if(r[d] >= t2) wsum += w2;
    if(r[d] >= t3) wsum += w3;
    if(r[d] >= t4) wsum += w4;
    Pr[d] = s[d] * wsum;
  }
}

// ---------------- W2[b,o,h*48+d] = sum_c projW[o,h*48+c] * P[b,h,c,d] ----------------
__global__ __launch_bounds__(384) void k_w2(const float* __restrict__ Wp, const float* __restrict__ P,
                                            float* __restrict__ W2){
  int t = threadIdx.x;            // 0..383 -> (h,d)
  int o = blockIdx.x, b = blockIdx.y;
  int h = t / 48, d = t % 48;
  const float* Pb = P + (size_t)(b*NH + h)*NC*NC + d;
  const float* Wr = Wp + o*DIM + h*NC;
  float s = 0.f;
  for(int c = 0; c < 48; c++) s = fmaf(Wr[c], Pb[c*NC], s);
  W2[((size_t)b*DIM + o)*DIM + t] = s;
}

extern "C" void kernel_launch(void* const* d_in, const int* in_sizes, int n_in,
                              void* d_out, int out_size, void* d_ws, size_t ws_size,
                              hipStream_t stream){
  const float* TEin = (const float*)d_in[0];
  const float* CEin = (const float*)d_in[1];
  const float* tn_w = (const float*)d_in[2];
  const float* tn_b = (const float*)d_in[3];
  const float* cn_w = (const float*)d_in[4];
  const float* cn_b = (const float*)d_in[5];
  const float* tq_w = (const float*)d_in[6];
  const float* tq_b = (const float*)d_in[7];
  const float* tq_dw= (const float*)d_in[8];
  const float* tq_db= (const float*)d_in[9];
  const float* ck_w = (const float*)d_in[10];
  const float* ck_b = (const float*)d_in[11];
  const float* ck_dw= (const float*)d_in[12];
  const float* ck_db= (const float*)d_in[13];
  const float* cv_w = (const float*)d_in[14];
  const float* cv_b = (const float*)d_in[15];
  const float* cv_dw= (const float*)d_in[16];
  const float* cv_db= (const float*)d_in[17];
  const float* temp = (const float*)d_in[18];
  const float* pj_w = (const float*)d_in[19];
  const float* pj_b = (const float*)d_in[20];
  const float* a1   = (const float*)d_in[21];
  const float* a2   = (const float*)d_in[22];
  const float* a3   = (const float*)d_in[23];
  const float* a4   = (const float*)d_in[24];

  char* ws = (char*)d_ws;
  const size_t S2 = (size_t)NB*DIM*HW*2;       // one bf16 tensor: 100,663,296 B
  bf16* q0 = (bf16*)(ws);
  bf16* k0 = (bf16*)(ws +   S2);
  bf16* v0 = (bf16*)(ws + 2*S2);
  bf16* q1 = (bf16*)(ws + 3*S2);
  bf16* k1 = (bf16*)(ws);          // reuses q0 (dead after dw-q)
  bf16* v1 = (bf16*)(ws +   S2);   // reuses k0 (dead after dw-k)
  char* sm = ws + 4*S2;
  float* mu   = (float*)(sm);                      // 2*131072 fp32
  float* rstd = (float*)(sm + 1048576);
  float* Wp   = (float*)(sm + 2097152);            // 3*384*384 fp32
  float* c1   = (float*)(sm + 3866624);            // 3*384
  float* c2   = (float*)(sm + 3871232);            // 3*384
  float* nq   = (float*)(sm + 3875840);            // 8*384
  float* nk   = (float*)(sm + 3888128);            // 8*384
  float* attn = (float*)(sm + 3900416);            // 64*48*48
  float* P    = (float*)(sm + 4490240);            // 64*48*48
  float* W2   = (float*)(sm + 5080064);            // 8*384*384

  // zero atomic targets (nq, nk, attn are contiguous: 153600 floats)
  k_zero<<<dim3(600), 256, 0, stream>>>(nq, 153600);
  // LN stats for both tensors
  k_stats<<<dim3(512, 2), 256, 0, stream>>>(TEin, CEin, mu, rstd);
  // fold LN into conv weights
  k_prep<<<dim3(384, 3), 64, 0, stream>>>(tq_w, ck_w, cv_w, tq_b, ck_b, cv_b,
                                          tn_w, tn_b, cn_w, cn_b, Wp, c1, c2);
  // conv1x1 (LN folded): q from T stats, k/v from C stats
  k_gemm<0><<<dim3(256,6,8), 256, 0, stream>>>(TEin, nullptr, Wp,        c1,        c2,        mu,      rstd,      nullptr, q0, nullptr);
  k_gemm<0><<<dim3(256,6,8), 256, 0, stream>>>(CEin, nullptr, Wp+MAT,    c1+DIM,    c2+DIM,    mu+NPIX, rstd+NPIX, nullptr, k0, nullptr);
  k_gemm<0><<<dim3(256,6,8), 256, 0, stream>>>(CEin, nullptr, Wp+2*MAT,  c1+2*DIM,  c2+2*DIM,  mu+NPIX, rstd+NPIX, nullptr, v0, nullptr);
  // depthwise 3x3 (+ sumsq accumulation for q,k norms)
  k_dw<<<dim3(64,384,8), 256, 0, stream>>>(q0, q1, tq_dw, tq_db, nq);
  k_dw<<<dim3(64,384,8), 256, 0, stream>>>(k0, k1, ck_dw, ck_db, nk);
  k_dw<<<dim3(64,384,8), 256, 0, stream>>>(v0, v1, cv_dw, cv_db, nullptr);
  // attn (unnormalized), 16-way K split with atomic accumulation
  k_attn<<<dim3(16,8,8), 64, 0, stream>>>(q1, k1, attn);
  // combined masked-softmax matrix P (norms + temperature folded here)
  k_pmat<<<dim3(8,8), 64, 0, stream>>>(attn, nq, nk, temp, a1, a2, a3, a4, P);
  // W2 = projW (per-head) @ P
  k_w2<<<dim3(384,8), 384, 0, stream>>>(pj_w, P, W2);
  // fused (P·v + proj + residual) as one GEMM: out = W2[b] @ v1 + proj_b + C_E_input
  k_gemm<1><<<dim3(256,6,8), 256, 0, stream>>>(nullptr, v1, W2, pj_b, nullptr, nullptr, nullptr, CEin, nullptr, (float*)d_out);
}